// Round 7
// baseline (102.296 us; speedup 1.0000x reference)
//
#include <hip/hip_runtime.h>
#include <hip/hip_bf16.h>

// Bloom MLP fused: h=X@W1^T+b1; g=gelu_tanh(h); out=g@W2^T+b2+residual
// X:[262144,64] f32, W1:[256,64], W2:[64,256], out:[262144,64] f32.
//
// Round 7: latency pipeline. __syncthreads drains vmcnt(0) (kills prefetch);
// replace with lgkmcnt(0)+raw s_barrier so global loads stay in flight across
// barriers. Manually unrolled 2-tile pipeline: X/R of tile1 issued before
// tile0's barrier, consumed after. GEMM2 split into 4 chains of 4 MFMA.
// grid 4096 x 2 tiles x 32 tokens. launch_bounds(256,3): no spills (round-5
// lesson: forced 40 VGPR -> 350MB scratch traffic).

typedef __attribute__((ext_vector_type(8))) short bf16x8;   // MFMA A/B frag
typedef __attribute__((ext_vector_type(4))) float f32x4;    // MFMA C/D frag
typedef __attribute__((ext_vector_type(4))) short short4v;  // packed 4x bf16

#define NBLK 4096    // 4096 blocks * 2 tiles * 32 tokens = 262144

__device__ __forceinline__ short f2bf(float x) {
    union { __hip_bfloat16 h; short s; } u;
    u.h = __float2bfloat16(x);      // compiler pairs into v_cvt_pk_bf16_f32
    return u.s;
}

__device__ __forceinline__ float bloom_gelu(float x) {
    // 0.5*x*(1+tanh(0.79788456*(x+0.044715*x^3))) = x*(1 - 1/(e^{2u}+1))
    // 2u*log2(e) = 2.30220842*x + 0.10294325*x^3  -> v_exp_f32 (2^x) direct
    float x2 = x * x;
    float t1 = __builtin_fmaf(0.10294325f, x2, 2.30220842f);
    float e  = __builtin_exp2f(x * t1);
    float r  = __builtin_amdgcn_rcpf(e + 1.0f);
    return x - x * r;
}

// LDS-visibility barrier that does NOT drain vmcnt: outstanding global loads
// (prefetched X/R) stay in flight across it. ds_write retirement needs only
// lgkmcnt(0). Trailing compiler fence stops LDS reads hoisting above.
__device__ __forceinline__ void block_sync_lds() {
    asm volatile("s_waitcnt lgkmcnt(0)" ::: "memory");
    __builtin_amdgcn_s_barrier();
    asm volatile("" ::: "memory");
}

// ---- pre-pass: convert W1 (16384 f32) then W2 (16384 f32) to bf16 in ws ----
__global__ __launch_bounds__(256) void cvt_weights(
    const float* __restrict__ W1, const float* __restrict__ W2,
    short* __restrict__ wsb)
{
    const int i4 = (blockIdx.x * 256 + threadIdx.x) * 4;   // 0..32764, step 4
    const float* src = (i4 < 16384) ? (W1 + i4) : (W2 + (i4 - 16384));
    float4 v = *(const float4*)src;
    short4v o;
    o[0] = f2bf(v.x); o[1] = f2bf(v.y); o[2] = f2bf(v.z); o[3] = f2bf(v.w);
    *(short4v*)(wsb + i4) = o;
}

template<bool PRE>
__global__ __launch_bounds__(256, 3) void bloom_mlp(
    const float* __restrict__ X,  const float* __restrict__ R,
    const float* __restrict__ W1, const float* __restrict__ b1,
    const float* __restrict__ W2, const float* __restrict__ b2,
    const short* __restrict__ Wb, float* __restrict__ out)
{
    // G[token][f] bf16, 32 tokens, row stride 264 (528B): ds_write_b64 at
    // 4 acc/bank, ds_read_b128 at 8 acc/bank -- the width minimum.
    __shared__ __align__(16) short Gs[32][264];

    const int tid  = threadIdx.x;
    const int wid  = tid >> 6;      // wave 0..3
    const int lane = tid & 63;
    const int q    = lane >> 4;     // 0..3
    const int c    = lane & 15;     // 0..15
    const int f0   = wid << 6;      // GEMM1 f-slice base

    const int row0 = (blockIdx.x << 6);        // tile 0: 32 tokens
    const int row1 = row0 + 32;                // tile 1

    auto ldX = [&](int row, int m, float4* x4) {
        const float* p = X + (size_t)(row + 16*m + c) * 64 + q*8;
        x4[0] = *(const float4*)(p);
        x4[1] = *(const float4*)(p + 4);
        x4[2] = *(const float4*)(p + 32);
        x4[3] = *(const float4*)(p + 36);
    };
    auto ldR = [&](int row, float4* r2) {
        r2[0] = *(const float4*)(R + (size_t)(row +      c) * 64 + 16*wid + 4*q);
        r2[1] = *(const float4*)(R + (size_t)(row + 16 + c) * 64 + 16*wid + 4*q);
    };

    // ---- issue tile-0 token loads FIRST (overlap weight-load latency) ----
    float4 x0a[4], x0b[4], r0[2];
    ldX(row0, 0, x0a); ldX(row0, 1, x0b); ldR(row0, r0);

    // ---- weight fragments, register-resident (bf16 pre-pass: 16B loads) ----
    bf16x8 w1f[4][2];   // GEMM1 A-op: lane holds W1[f0+16t+c][kb*32+q*8..+7]
    bf16x8 w2f[8];      // GEMM2 A-op: lane holds W2[16wid+c][kb*32+q*8..+7]
    if constexpr (PRE) {
        const short* W1b = Wb;
        const short* W2b = Wb + 16384;
#pragma unroll
        for (int t = 0; t < 4; ++t)
#pragma unroll
            for (int kb = 0; kb < 2; ++kb)
                w1f[t][kb] = *(const bf16x8*)&W1b[(f0 + 16*t + c) * 64 + kb*32 + q*8];
#pragma unroll
        for (int kb = 0; kb < 8; ++kb)
            w2f[kb] = *(const bf16x8*)&W2b[(16*wid + c) * 256 + kb*32 + q*8];
    } else {
#pragma unroll
        for (int t = 0; t < 4; ++t)
#pragma unroll
            for (int kb = 0; kb < 2; ++kb) {
                const float* p = W1 + (size_t)(f0 + 16*t + c) * 64 + kb*32 + q*8;
                float4 lo = *(const float4*)p, hi = *(const float4*)(p + 4);
                bf16x8 f;
                f[0]=f2bf(lo.x); f[1]=f2bf(lo.y); f[2]=f2bf(lo.z); f[3]=f2bf(lo.w);
                f[4]=f2bf(hi.x); f[5]=f2bf(hi.y); f[6]=f2bf(hi.z); f[7]=f2bf(hi.w);
                w1f[t][kb] = f;
            }
#pragma unroll
        for (int kb = 0; kb < 8; ++kb) {
            const float* p = W2 + (size_t)(16*wid + c) * 256 + kb*32 + q*8;
            float4 lo = *(const float4*)p, hi = *(const float4*)(p + 4);
            bf16x8 f;
            f[0]=f2bf(lo.x); f[1]=f2bf(lo.y); f[2]=f2bf(lo.z); f[3]=f2bf(lo.w);
            f[4]=f2bf(hi.x); f[5]=f2bf(hi.y); f[6]=f2bf(hi.z); f[7]=f2bf(hi.w);
            w2f[kb] = f;
        }
    }

    const float4 b2q = *(const float4*)(b2 + 16*wid + 4*q);

    auto cvt8 = [](const float4& lo, const float4& hi) {
        bf16x8 f;
        f[0]=f2bf(lo.x); f[1]=f2bf(lo.y); f[2]=f2bf(lo.z); f[3]=f2bf(lo.w);
        f[4]=f2bf(hi.x); f[5]=f2bf(hi.y); f[6]=f2bf(hi.z); f[7]=f2bf(hi.w);
        return f;
    };

    // GEMM1 for one 16-token subtile: D[f_local=4q+r][token=c] per f-tile t
    auto gemm1 = [&](int m, const float4* x4) {
        bf16x8 a0 = cvt8(x4[0], x4[1]);
        bf16x8 a1 = cvt8(x4[2], x4[3]);
#pragma unroll
        for (int t = 0; t < 4; ++t) {
            const float4 b1q = *(const float4*)(b1 + f0 + 16*t + 4*q);
            f32x4 acc = {0.f, 0.f, 0.f, 0.f};
            acc = __builtin_amdgcn_mfma_f32_16x16x32_bf16(w1f[t][0], a0, acc, 0, 0, 0);
            acc = __builtin_amdgcn_mfma_f32_16x16x32_bf16(w1f[t][1], a1, acc, 0, 0, 0);
            short4v g;
#pragma unroll
            for (int r = 0; r < 4; ++r)
                g[r] = f2bf(bloom_gelu(acc[r] + b1q[r]));
            *(short4v*)&Gs[16*m + c][f0 + 16*t + 4*q] = g;   // 8B packed
        }
    };

    // GEMM2 + epilogue: wave owns d-tile [16wid,16wid+16); 4 chains x 4 MFMA
    auto gemm2 = [&](int row, const float4* r2) {
        f32x4 aA[2] = {{0.f,0.f,0.f,0.f},{0.f,0.f,0.f,0.f}};
        f32x4 aB[2] = {{0.f,0.f,0.f,0.f},{0.f,0.f,0.f,0.f}};
#pragma unroll
        for (int kb = 0; kb < 4; ++kb)
#pragma unroll
            for (int m = 0; m < 2; ++m) {
                bf16x8 ga = *(const bf16x8*)&Gs[16*m + c][kb*32 + q*8];
                aA[m] = __builtin_amdgcn_mfma_f32_16x16x32_bf16(w2f[kb], ga, aA[m], 0, 0, 0);
            }
#pragma unroll
        for (int kb = 4; kb < 8; ++kb)
#pragma unroll
            for (int m = 0; m < 2; ++m) {
                bf16x8 ga = *(const bf16x8*)&Gs[16*m + c][kb*32 + q*8];
                aB[m] = __builtin_amdgcn_mfma_f32_16x16x32_bf16(w2f[kb], ga, aB[m], 0, 0, 0);
            }
#pragma unroll
        for (int m = 0; m < 2; ++m) {
            const size_t off = (size_t)(row + 16*m + c) * 64 + 16*wid + 4*q;
            float4 o;
            o.x = aA[m][0] + aB[m][0] + b2q.x + r2[m].x;
            o.y = aA[m][1] + aB[m][1] + b2q.y + r2[m].y;
            o.z = aA[m][2] + aB[m][2] + b2q.z + r2[m].z;
            o.w = aA[m][3] + aB[m][3] + b2q.w + r2[m].w;
            *(float4*)(out + off) = o;
        }
    };

    // ================= pipeline =================
    gemm1(0, x0a);
    gemm1(1, x0b);

    // tile-1 token loads issued NOW: they stay in flight across both barriers
    // and all of GEMM2/epilogue of tile 0 (raw barrier does not drain vmcnt).
    float4 x1a[4], x1b[4], r1[2];
    ldX(row1, 0, x1a); ldX(row1, 1, x1b); ldR(row1, r1);

    block_sync_lds();          // Gs (tile 0) written -> readable

    gemm2(row0, r0);

    block_sync_lds();          // Gs WAR: tile-0 reads done before tile-1 writes

    gemm1(0, x1a);
    gemm1(1, x1b);

    block_sync_lds();          // Gs (tile 1) written -> readable

    gemm2(row1, r1);
}

extern "C" void kernel_launch(void* const* d_in, const int* in_sizes, int n_in,
                              void* d_out, int out_size, void* d_ws, size_t ws_size,
                              hipStream_t stream) {
    const float* X  = (const float*)d_in[0];
    const float* R  = (const float*)d_in[1];
    const float* W1 = (const float*)d_in[2];
    const float* b1 = (const float*)d_in[3];
    const float* W2 = (const float*)d_in[4];
    const float* b2 = (const float*)d_in[5];
    float* out = (float*)d_out;
    (void)in_sizes; (void)n_in; (void)out_size;

    if (ws_size >= 65536) {
        short* wsb = (short*)d_ws;
        cvt_weights<<<32, 256, 0, stream>>>(W1, W2, wsb);
        bloom_mlp<true><<<NBLK, 256, 0, stream>>>(X, R, W1, b1, W2, b2, wsb, out);
    } else {
        bloom_mlp<false><<<NBLK, 256, 0, stream>>>(X, R, W1, b1, W2, b2, nullptr, out);
    }
}

// Round 8
// 69.971 us; speedup vs baseline: 1.4620x; 1.4620x over previous
//
#include <hip/hip_runtime.h>
#include <hip/hip_bf16.h>

// Bloom MLP fused: h=X@W1^T+b1; g=gelu_tanh(h); out=g@W2^T+b2+residual
// X:[262144,64] f32, W1:[256,64], W2:[64,256], out:[262144,64] f32.
//
// Round 8 = round-4 frame (best: 85us dispatch) + X staged via
// global_load_lds into a swizzled LDS buffer, issued one full phase ahead:
//  - Xb[4096] f32, filled by 4x global_load_lds(width16)/wave; source addr
//    pre-swizzled (16B slot ^= row&15), ds_read applies same XOR (T21).
//  - next-tile staging issued right after the mid barrier -> HBM latency
//    hides under GEMM2+epilogue. Zero VGPR cost (vs 64 VGPR reg-prefetch).
//  - mid barrier: lgkmcnt(0)+s_barrier (non-draining). End-of-tile:
//    __syncthreads (staging is cross-wave-consumed; per-wave vmcnt must
//    drain BEFORE the barrier).
// grid 2048 x 2 tiles x 64 tokens; launch_bounds(256,4); est ~90 VGPR.

typedef __attribute__((ext_vector_type(8))) short bf16x8;   // MFMA A/B frag
typedef __attribute__((ext_vector_type(4))) float f32x4;    // MFMA C/D frag
typedef __attribute__((ext_vector_type(4))) short short4v;  // packed 4x bf16

#define NBLK  2048
#define TILES 2      // 2048 blocks * 2 tiles * 64 tokens = 262144

__device__ __forceinline__ short f2bf(float x) {
    union { __hip_bfloat16 h; short s; } u;
    u.h = __float2bfloat16(x);      // compiler pairs into v_cvt_pk_bf16_f32
    return u.s;
}

__device__ __forceinline__ float bloom_gelu(float x) {
    // 0.5*x*(1+tanh(0.79788456*(x+0.044715*x^3))) = x*(1 - 1/(e^{2u}+1))
    // 2u*log2(e) = 2.30220842*x + 0.10294325*x^3 -> v_exp_f32 (2^x) direct
    float x2 = x * x;
    float t1 = __builtin_fmaf(0.10294325f, x2, 2.30220842f);
    float e  = __builtin_exp2f(x * t1);
    float r  = __builtin_amdgcn_rcpf(e + 1.0f);
    return x - x * r;
}

// async global->LDS, 16B per lane. Dest must be lane-linear (base+lane*16).
__device__ __forceinline__ void gload_lds16(const float* src, float* dst) {
    __builtin_amdgcn_global_load_lds(
        (const __attribute__((address_space(1))) void*)src,
        (__attribute__((address_space(3))) void*)dst, 16, 0, 0);
}

// non-draining barrier: LDS visibility only, vmem stays in flight
__device__ __forceinline__ void bar_lgkm() {
    asm volatile("s_waitcnt lgkmcnt(0)" ::: "memory");
    __builtin_amdgcn_s_barrier();
    asm volatile("" ::: "memory");
}

// ---- pre-pass: convert W1 (16384 f32) then W2 (16384 f32) to bf16 in ws ----
__global__ __launch_bounds__(256) void cvt_weights(
    const float* __restrict__ W1, const float* __restrict__ W2,
    short* __restrict__ wsb)
{
    const int i4 = (blockIdx.x * 256 + threadIdx.x) * 4;   // 0..32764, step 4
    const float* src = (i4 < 16384) ? (W1 + i4) : (W2 + (i4 - 16384));
    float4 v = *(const float4*)src;
    short4v o;
    o[0] = f2bf(v.x); o[1] = f2bf(v.y); o[2] = f2bf(v.z); o[3] = f2bf(v.w);
    *(short4v*)(wsb + i4) = o;
}

template<bool PRE>
__global__ __launch_bounds__(256, 4) void bloom_mlp(
    const float* __restrict__ X,  const float* __restrict__ R,
    const float* __restrict__ W1, const float* __restrict__ b1,
    const float* __restrict__ W2, const float* __restrict__ b2,
    const short* __restrict__ Wb, float* __restrict__ out)
{
    // Gs: G[token][f] bf16, row stride 264 (528B) -> uniform bank spread.
    // Xb: staged X tile, 64 tok x 64 f f32, 16B-slot XOR-swizzled by row.
    __shared__ __align__(16) short Gs[64][264];   // 33792 B
    __shared__ __align__(16) float Xb[4096];      // 16384 B

    const int tid  = threadIdx.x;
    const int wid  = tid >> 6;      // wave 0..3
    const int lane = tid & 63;
    const int q    = lane >> 4;     // 0..3
    const int c    = lane & 15;     // 0..15
    const int f0   = wid << 6;      // GEMM1 f-slice base

    // stage one 64-token X tile into Xb.
    // dest (linear): float idx didx = j*1024 + tid*4
    // src slot swizzle: 16B slot hd=(didx>>2)&15 holds source slot hd^(row&15)
    auto stage_x = [&](int rowbase) {
#pragma unroll
        for (int j = 0; j < 4; ++j) {
            const int didx = j * 1024 + tid * 4;
            const int row  = didx >> 6;                    // 0..63
            const int hs   = ((didx >> 2) & 15) ^ (row & 15);
            gload_lds16(X + (size_t)(rowbase + row) * 64 + (hs << 2), &Xb[didx]);
        }
    };

    const int row0 = blockIdx.x << 7;     // 128 tokens per block
    stage_x(row0);                        // X tile 0 in flight immediately

    // ---- weight fragments, register-resident across tiles ----
    bf16x8 w1f[4][2];   // GEMM1 A-op: lane holds W1[f0+16t+c][kb*32+q*8..+7]
    bf16x8 w2f[8];      // GEMM2 A-op: lane holds W2[16wid+c][kb*32+q*8..+7]
    if constexpr (PRE) {
        const short* W1b = Wb;
        const short* W2b = Wb + 16384;
#pragma unroll
        for (int t = 0; t < 4; ++t)
#pragma unroll
            for (int kb = 0; kb < 2; ++kb)
                w1f[t][kb] = *(const bf16x8*)&W1b[(f0 + 16*t + c) * 64 + kb*32 + q*8];
#pragma unroll
        for (int kb = 0; kb < 8; ++kb)
            w2f[kb] = *(const bf16x8*)&W2b[(16*wid + c) * 256 + kb*32 + q*8];
    } else {
#pragma unroll
        for (int t = 0; t < 4; ++t)
#pragma unroll
            for (int kb = 0; kb < 2; ++kb) {
                const float* p = W1 + (size_t)(f0 + 16*t + c) * 64 + kb*32 + q*8;
                float4 lo = *(const float4*)p, hi = *(const float4*)(p + 4);
                bf16x8 f;
                f[0]=f2bf(lo.x); f[1]=f2bf(lo.y); f[2]=f2bf(lo.z); f[3]=f2bf(lo.w);
                f[4]=f2bf(hi.x); f[5]=f2bf(hi.y); f[6]=f2bf(hi.z); f[7]=f2bf(hi.w);
                w1f[t][kb] = f;
            }
#pragma unroll
        for (int kb = 0; kb < 8; ++kb) {
            const float* p = W2 + (size_t)(16*wid + c) * 256 + kb*32 + q*8;
            float4 lo = *(const float4*)p, hi = *(const float4*)(p + 4);
            bf16x8 f;
            f[0]=f2bf(lo.x); f[1]=f2bf(lo.y); f[2]=f2bf(lo.z); f[3]=f2bf(lo.w);
            f[4]=f2bf(hi.x); f[5]=f2bf(hi.y); f[6]=f2bf(hi.z); f[7]=f2bf(hi.w);
            w2f[kb] = f;
        }
    }

    const float4 b2q = *(const float4*)(b2 + 16*wid + 4*q);

    __syncthreads();   // X tile 0 staged (drains own vmcnt) + all waves synced

    for (int it = 0; it < TILES; ++it) {
        const int rowT = row0 + (it << 6);

        // ---- GEMM1 + GELU -> Gs, X from swizzled Xb ----
#pragma unroll
        for (int m = 0; m < 4; ++m) {
            const int xrow = (16*m + c) << 6;
            bf16x8 a1[2];
#pragma unroll
            for (int kb = 0; kb < 2; ++kb) {
                const int h0 = 8*kb + 2*q;                 // wanted 16B slots
                const float4 lo = *(const float4*)&Xb[xrow + (((h0    ) ^ c) << 2)];
                const float4 hi = *(const float4*)&Xb[xrow + (((h0 + 1) ^ c) << 2)];
                bf16x8 f;
                f[0]=f2bf(lo.x); f[1]=f2bf(lo.y); f[2]=f2bf(lo.z); f[3]=f2bf(lo.w);
                f[4]=f2bf(hi.x); f[5]=f2bf(hi.y); f[6]=f2bf(hi.z); f[7]=f2bf(hi.w);
                a1[kb] = f;
            }
            // D[f_local=4q+r][token=c] per f-tile t
#pragma unroll
            for (int t = 0; t < 4; ++t) {
                const float4 b1q = *(const float4*)(b1 + f0 + 16*t + 4*q);
                f32x4 acc = {0.f, 0.f, 0.f, 0.f};
                acc = __builtin_amdgcn_mfma_f32_16x16x32_bf16(w1f[t][0], a1[0], acc, 0, 0, 0);
                acc = __builtin_amdgcn_mfma_f32_16x16x32_bf16(w1f[t][1], a1[1], acc, 0, 0, 0);
                short4v g;
#pragma unroll
                for (int r = 0; r < 4; ++r)
                    g[r] = f2bf(bloom_gelu(acc[r] + b1q[r]));
                *(short4v*)&Gs[16*m + c][f0 + 16*t + 4*q] = g;   // 8B packed
            }
        }

        bar_lgkm();   // Gs ready; all waves done reading Xb (non-draining)

        // next X tile issued NOW -> lands during GEMM2 + epilogue
        if (it + 1 < TILES) stage_x(rowT + 64);

        // ---- GEMM2: wave owns d-tile [16wid,16wid+16) over K=256 ----
        // D[d_local=4q+r][token=c]; 2 chains (kb 0-3 / 4-7) for ILP
        f32x4 aA[4] = {{0,0,0,0},{0,0,0,0},{0,0,0,0},{0,0,0,0}};
        f32x4 aB[4] = {{0,0,0,0},{0,0,0,0},{0,0,0,0},{0,0,0,0}};
#pragma unroll
        for (int kb = 0; kb < 4; ++kb)
#pragma unroll
            for (int m = 0; m < 4; ++m) {
                bf16x8 ga = *(const bf16x8*)&Gs[16*m + c][kb*32 + q*8];
                aA[m] = __builtin_amdgcn_mfma_f32_16x16x32_bf16(w2f[kb], ga, aA[m], 0, 0, 0);
            }
#pragma unroll
        for (int kb = 4; kb < 8; ++kb)
#pragma unroll
            for (int m = 0; m < 4; ++m) {
                bf16x8 ga = *(const bf16x8*)&Gs[16*m + c][kb*32 + q*8];
                aB[m] = __builtin_amdgcn_mfma_f32_16x16x32_bf16(w2f[kb], ga, aB[m], 0, 0, 0);
            }

        // ---- epilogue: out[rowT+16m+c][16wid+4q..+3], R loaded here ----
        float4 r4[4];
#pragma unroll
        for (int m = 0; m < 4; ++m)
            r4[m] = *(const float4*)(R + (size_t)(rowT + 16*m + c) * 64 + 16*wid + 4*q);
#pragma unroll
        for (int m = 0; m < 4; ++m) {
            float4 o;
            o.x = aA[m][0] + aB[m][0] + b2q.x + r4[m].x;
            o.y = aA[m][1] + aB[m][1] + b2q.y + r4[m].y;
            o.z = aA[m][2] + aB[m][2] + b2q.z + r4[m].z;
            o.w = aA[m][3] + aB[m][3] + b2q.w + r4[m].w;
            *(float4*)(out + (size_t)(rowT + 16*m + c) * 64 + 16*wid + 4*q) = o;
        }

        // staging is cross-wave-consumed: drain own vmcnt BEFORE barrier
        // (__syncthreads = vmcnt(0)+lgkmcnt(0)+s_barrier). Also Gs WAR.
        if (it + 1 < TILES) __syncthreads();
    }
}

extern "C" void kernel_launch(void* const* d_in, const int* in_sizes, int n_in,
                              void* d_out, int out_size, void* d_ws, size_t ws_size,
                              hipStream_t stream) {
    const float* X  = (const float*)d_in[0];
    const float* R  = (const float*)d_in[1];
    const float* W1 = (const float*)d_in[2];
    const float* b1 = (const float*)d_in[3];
    const float* W2 = (const float*)d_in[4];
    const float* b2 = (const float*)d_in[5];
    float* out = (float*)d_out;
    (void)in_sizes; (void)n_in; (void)out_size;

    if (ws_size >= 65536) {
        short* wsb = (short*)d_ws;
        cvt_weights<<<32, 256, 0, stream>>>(W1, W2, wsb);
        bloom_mlp<true><<<NBLK, 256, 0, stream>>>(X, R, W1, b1, W2, b2, wsb, out);
    } else {
        bloom_mlp<false><<<NBLK, 256, 0, stream>>>(X, R, W1, b1, W2, b2, nullptr, out);
    }
}